// Round 8
// baseline (224.248 us; speedup 1.0000x reference)
//
#include <hip/hip_runtime.h>
#include <hip/hip_bf16.h>

#define BDIM 2
#define SDIM 1024
#define DDIM 2048
#define NH 16
#define NKV 8
#define HD 128
#define WINDOW 256

typedef __bf16 bf16;
typedef __bf16 bf16x4 __attribute__((ext_vector_type(4)));
typedef __bf16 bf16x8 __attribute__((ext_vector_type(8)));
typedef float f32x4 __attribute__((ext_vector_type(4)));

#define L2E 1.44269504088896341f

__device__ inline bf16x8 load8(const bf16* p) { return *reinterpret_cast<const bf16x8*>(p); }

// async global->LDS, 16 B per lane (LDS dest = wave-uniform base + lane*16)
__device__ __forceinline__ void gl_lds16(const bf16* g, bf16* l) {
  __builtin_amdgcn_global_load_lds(
      (__attribute__((address_space(1))) void*)g,
      (__attribute__((address_space(3))) void*)l,
      16, 0, 0);
}

// ---------------- prep v2: vectorized weight transposes (z=0..3) + x cast (z=4) ----------------
// Transposes: 64x64 tiles, float4 reads (16B/lane), bf16x4 writes (8B/lane, 4x old width).
// Cast: float4 -> bf16x4, fully coalesced, 16 elems/thread.
__global__ __launch_bounds__(256) void prep(const float* __restrict__ x,
                                            const float* __restrict__ wq,
                                            const float* __restrict__ wk,
                                            const float* __restrict__ wv,
                                            const float* __restrict__ wo,
                                            bf16* __restrict__ xb,
                                            bf16* __restrict__ wqkvT,
                                            bf16* __restrict__ woT) {
  __shared__ bf16 tl[64][72];   // row stride 144B: 8B-aligned rows for bf16x4 ops
  int z = blockIdx.z;
  int t = threadIdx.x;
  if (z == 4) {  // cast x -> xb, 16 elems/thread, coalesced
    long base = ((long)(blockIdx.y * 32 + blockIdx.x)) * 4096;
    const float* xs = x + base;
    bf16* xo = xb + base;
#pragma unroll
    for (int e = 0; e < 4; ++e) {
      float4 a = *(const float4*)&xs[(e * 256 + t) * 4];
      bf16x4 o;
      o[0] = (bf16)a.x; o[1] = (bf16)a.y; o[2] = (bf16)a.z; o[3] = (bf16)a.w;
      *(bf16x4*)&xo[(e * 256 + t) * 4] = o;
    }
    return;
  }
  const float* src; bf16* dst; int C;
  if (z == 0)      { src = wq; dst = wqkvT;                 C = 2048; }
  else if (z == 1) { src = wk; dst = wqkvT + 2048L * 2048;  C = 1024; }
  else if (z == 2) { src = wv; dst = wqkvT + 3072L * 2048;  C = 1024; }
  else             { src = wo; dst = woT;                   C = 2048; }
  int c0 = blockIdx.x * 64, r0 = blockIdx.y * 64;
  if (c0 >= C) return;
  int tx = t & 15, ty = t >> 4;   // 16 x 16 thread layout
#pragma unroll
  for (int rr = 0; rr < 4; ++rr) {
    int row = ty + rr * 16;
    float4 a = *(const float4*)&src[(long)(r0 + row) * C + c0 + tx * 4];
    bf16x4 o;
    o[0] = (bf16)a.x; o[1] = (bf16)a.y; o[2] = (bf16)a.z; o[3] = (bf16)a.w;
    *(bf16x4*)&tl[row][tx * 4] = o;
  }
  __syncthreads();
#pragma unroll
  for (int rr = 0; rr < 4; ++rr) {
    int cc = ty + rr * 16;
    bf16x4 o;
#pragma unroll
    for (int e = 0; e < 4; ++e) o[e] = tl[tx * 4 + e][cc];
    *(bf16x4*)&dst[(long)(c0 + cc) * 2048 + r0 + tx * 4] = o;
  }
}

// ---------------- out-proj GEMM v2: 128x128 tiles, 8 waves, counted-vmcnt double-buffered ------
// 256 blocks = 1/CU. Schedule: prologue 4 loads/thread; per iter issue 2 -> vmcnt(2) retires old
// tile's 4 -> cmp(ks=0) -> issue 2 -> cmp(ks=32) -> barrier. Invariant: 4 outstanding per iter.
__global__ __launch_bounds__(512) void gemm_bt128(const bf16* __restrict__ A,
                                                  const bf16* __restrict__ Bt,
                                                  float* __restrict__ C,
                                                  int M, int N, int K) {
  __shared__ bf16 smem[2 * 16384];  // per buffer: As 128*64 + Bs 128*64 = 16384 elems = 32 KB
  int t = threadIdx.x;
  int wid = t >> 6, lane = t & 63;
  int wm = (wid >> 2) * 64, wn = (wid & 3) * 32;  // 2M x 4N waves, 64x32 per wave
  int fm = lane & 15, quad = lane >> 4;

  // XCD-chunked bijective swizzle over 256 wgs
  int wg = blockIdx.y * 16 + blockIdx.x;
  int swz = (wg & 7) * 32 + (wg >> 3);
  int by = swz >> 4, bx = swz & 15;
  int m0 = by * 128, n0 = bx * 128;

  const bf16* Ag = A + (long)m0 * K;
  const bf16* Bg = Bt + (long)n0 * K;

  f32x4 acc[4][2] = {};

  auto stA = [&](bf16* dst, int k0, int p) {
    int idx = p * 512 + t;             // idx 0..1023 -> row 0..127
    int row = idx >> 3, ccs = idx & 7;
    int gcol = ((ccs ^ (row & 7)) * 8);
    gl_lds16(&Ag[(long)row * K + k0 + gcol], &dst[idx * 8]);
  };
  auto stB = [&](bf16* dst, int k0, int p) {
    int idx = p * 512 + t;
    int row = idx >> 3, ccs = idx & 7;
    int gcol = ((ccs ^ (row & 7)) * 8);
    gl_lds16(&Bg[(long)row * K + k0 + gcol], &dst[idx * 8]);
  };
  auto cmp = [&](const bf16* As, const bf16* Bs, int ks) {
    int cc = (ks >> 3) + quad;
    bf16x8 af[4], bfr[2];
    for (int i = 0; i < 4; ++i) {
      int fr = wm + i * 16 + fm;
      af[i] = load8(&As[(fr * 8 + (cc ^ (fr & 7))) * 8]);
    }
    for (int j = 0; j < 2; ++j) {
      int fr = wn + j * 16 + fm;
      bfr[j] = load8(&Bs[(fr * 8 + (cc ^ (fr & 7))) * 8]);
    }
    __builtin_amdgcn_s_setprio(1);
    for (int i = 0; i < 4; ++i)
      for (int j = 0; j < 2; ++j)
        acc[i][j] = __builtin_amdgcn_mfma_f32_16x16x32_bf16(af[i], bfr[j], acc[i][j], 0, 0, 0);
    __builtin_amdgcn_s_setprio(0);
  };

  {  // prologue: stage K-tile 0 (4 loads/thread)
    bf16* As = smem; bf16* Bs = smem + 8192;
    stA(As, 0, 0); stA(As, 0, 1);
    stB(Bs, 0, 0); stB(Bs, 0, 1);
  }
  const int NT = K / 64;
  for (int kt = 0; kt < NT; ++kt) {
    int cur = kt & 1;
    bf16* As = smem + cur * 16384;
    bf16* Bs = As + 8192;
    if (kt + 1 < NT) {
      bf16* An = smem + (cur ^ 1) * 16384;
      bf16* Bn = An + 8192;
      int kn = (kt + 1) * 64;
      stA(An, kn, 0); stB(Bn, kn, 0);
      asm volatile("s_waitcnt vmcnt(2)\n\ts_barrier" ::: "memory");
      cmp(As, Bs, 0);
      stA(An, kn, 1); stB(Bn, kn, 1);
      cmp(As, Bs, 32);
      asm volatile("s_barrier" ::: "memory");
    } else {
      asm volatile("s_waitcnt vmcnt(0)\n\ts_barrier" ::: "memory");
      cmp(As, Bs, 0);
      cmp(As, Bs, 32);
    }
  }
  for (int i = 0; i < 4; ++i)
    for (int r = 0; r < 4; ++r) {
      int row = m0 + wm + i * 16 + quad * 4 + r;
      for (int j = 0; j < 2; ++j) {
        int col = n0 + wn + j * 16 + fm;
        C[(long)row * N + col] = acc[i][j][r];
      }
    }
}

// ---------------- QKV GEMM, 128x256 tile, 8 waves, counted-vmcnt double-buffered ----------------
#define VPITCH 130
__global__ __launch_bounds__(512) void gemm_qkv(const bf16* __restrict__ A,
                                                const bf16* __restrict__ Bt,
                                                const float* __restrict__ fc,
                                                const float* __restrict__ fs,
                                                bf16* __restrict__ q0,
                                                bf16* __restrict__ k1,
                                                bf16* __restrict__ k2,
                                                bf16* __restrict__ vT) {
  const int K = 2048;
  __shared__ bf16 smem[2 * 24576];
  int t = threadIdx.x;
  int wid = t >> 6, lane = t & 63;
  int wm = (wid >> 2) * 64, wn = (wid & 3) * 64;
  int fm = lane & 15, quad = lane >> 4;

  int wg = blockIdx.y * 16 + blockIdx.x;
  int swz = (wg & 7) * 32 + (wg >> 3);
  int by = swz >> 4, bx = swz & 15;
  int m0 = by * 128, n0 = bx * 256;

  const bf16* Ag = A + (long)m0 * K;
  const bf16* Bg = Bt + (long)n0 * K;

  f32x4 acc[4][4] = {};

  auto stA = [&](bf16* dst, int k0, int p) {
    int idx = p * 512 + t;
    int row = idx >> 3, ccs = idx & 7;
    int gcol = ((ccs ^ (row & 7)) * 8);
    gl_lds16(&Ag[(long)row * K + k0 + gcol], &dst[idx * 8]);
  };
  auto stB = [&](bf16* dst, int k0, int p) {
    int idx = p * 512 + t;
    int row = idx >> 3, ccs = idx & 7;
    int gcol = ((ccs ^ (row & 7)) * 8);
    gl_lds16(&Bg[(long)row * K + k0 + gcol], &dst[idx * 8]);
  };
  auto cmp = [&](const bf16* As, const bf16* Bs, int ks) {
    int cc = (ks >> 3) + quad;
    bf16x8 af[4], bfr[4];
    for (int i = 0; i < 4; ++i) {
      int fr = wm + i * 16 + fm;
      af[i] = load8(&As[(fr * 8 + (cc ^ (fr & 7))) * 8]);
    }
    for (int j = 0; j < 4; ++j) {
      int fr = wn + j * 16 + fm;
      bfr[j] = load8(&Bs[(fr * 8 + (cc ^ (fr & 7))) * 8]);
    }
    __builtin_amdgcn_s_setprio(1);
    for (int i = 0; i < 4; ++i)
      for (int j = 0; j < 4; ++j)
        acc[i][j] = __builtin_amdgcn_mfma_f32_16x16x32_bf16(af[i], bfr[j], acc[i][j], 0, 0, 0);
    __builtin_amdgcn_s_setprio(0);
  };

  {
    bf16* As = smem; bf16* Bs = smem + 8192;
    stA(As, 0, 0); stA(As, 0, 1);
    stB(Bs, 0, 0); stB(Bs, 0, 1); stB(Bs, 0, 2); stB(Bs, 0, 3);
  }
  const int NT = K / 64;
  for (int kt = 0; kt < NT; ++kt) {
    int cur = kt & 1;
    bf16* As = smem + cur * 24576;
    bf16* Bs = As + 8192;
    if (kt + 1 < NT) {
      bf16* An = smem + (cur ^ 1) * 24576;
      bf16* Bn = An + 8192;
      int kn = (kt + 1) * 64;
      stA(An, kn, 0); stA(An, kn, 1); stB(Bn, kn, 0);
      asm volatile("s_waitcnt vmcnt(3)\n\ts_barrier" ::: "memory");
      cmp(As, Bs, 0);
      stB(Bn, kn, 1); stB(Bn, kn, 2); stB(Bn, kn, 3);
      cmp(As, Bs, 32);
      asm volatile("s_barrier" ::: "memory");
    } else {
      asm volatile("s_waitcnt vmcnt(0)\n\ts_barrier" ::: "memory");
      cmp(As, Bs, 0);
      cmp(As, Bs, 32);
    }
  }

  if (n0 < 2048) {  // ---- Q: raw scaled store (no rope)
    const float scale = 0.08838834764831845f;
    for (int i = 0; i < 4; ++i)
      for (int r = 0; r < 4; ++r) {
        int row = m0 + wm + i * 16 + quad * 4 + r;
        for (int j = 0; j < 4; ++j) {
          int gc = n0 + wn + j * 16 + fm;
          q0[(long)row * 2048 + gc] = (bf16)(acc[i][j][r] * scale);
        }
      }
  } else if (n0 < 3072) {  // ---- K: k1 = R(s)k, k2 = R(-W)k
    float sgn = (lane & 1) ? 1.f : -1.f;
    float cwj[4], swj[4];
    for (int j = 0; j < 4; ++j) {
      int dp = ((wn + j * 16 + fm) & 127) >> 1;
      cwj[j] = fc[WINDOW * 64 + dp];
      swj[j] = fs[WINDOW * 64 + dp] * (-sgn);
    }
    for (int i = 0; i < 4; ++i)
      for (int r = 0; r < 4; ++r) {
        int row = m0 + wm + i * 16 + quad * 4 + r;
        int s = row & (SDIM - 1);
        for (int j = 0; j < 4; ++j) {
          int kc = n0 - 2048 + wn + j * 16 + fm;
          int dp = (kc & 127) >> 1;
          float v = acc[i][j][r];
          float pp = __shfl_xor(v, 1, 64);
          float c = fc[s * 64 + dp];
          float sn = fs[s * 64 + dp] * sgn;
          long dst = (long)row * 1024 + kc;
          k1[dst] = (bf16)(v * c + pp * sn);
          k2[dst] = (bf16)(v * cwj[j] + pp * swj[j]);
        }
      }
  } else {  // ---- V: two 128-col halves through reused staging LDS
    int vv0 = (n0 - 3072) >> 7;
    int s0l = m0 & (SDIM - 1);
    int bq = m0 >> 10;
    for (int half = 0; half < 2; ++half) {
      __syncthreads();
      if (((wn >> 7) & 1) == half) {
        for (int i = 0; i < 4; ++i)
          for (int j = 0; j < 4; ++j) {
            int col = (wn & 127) + j * 16 + fm;
            for (int r = 0; r < 4; ++r) {
              int rl = wm + i * 16 + quad * 4 + r;
              smem[col * VPITCH + rl] = (bf16)acc[i][j][r];
            }
          }
      }
      __syncthreads();
      bf16* vtg = vT + ((long)(bq * NKV + vv0 + half)) * 128 * 1024;
      for (int p = 0; p < 4; ++p) {
        int c = p * 512 + t;
        int d = c >> 4, sc = (c & 15) * 8;
        *(bf16x8*)&vtg[(long)d * 1024 + s0l + sc] = *(bf16x8*)&smem[d * VPITCH + sc];
      }
    }
  }
}

// ---------------- Flash attention v8 (verified best: 48.3-49.0 us) -----------------------------
// Segments: each key block needs exactly ONE K tile (k2 far / k1 window); overlap block split
// into two segments with disjoint masks. Double-buffered K+V staging, counted vmcnt(8) keeps
// next segment's 8 loads in flight across the barrier.
__global__ __launch_bounds__(256) void attn_kernel(const bf16* __restrict__ q0,
                                                   const bf16* __restrict__ k1,
                                                   const bf16* __restrict__ k2,
                                                   const bf16* __restrict__ vT,
                                                   const float* __restrict__ fc,
                                                   const float* __restrict__ fs,
                                                   bf16* __restrict__ aout) {
  __shared__ bf16 Kb[2][8192];   // [buf][64 key rows x 128 d] swizzled
  __shared__ bf16 Vb[2][8192];   // [buf][128 d x 64 keys] swizzled
  __shared__ bf16 Pl[4][16][72];
  __shared__ float stats[4][16];

  int h = blockIdx.y;
  int b = blockIdx.z;
  int tile = b ? (15 - blockIdx.x) : blockIdx.x;
  int kv = h >> 1;  // NREP = 2
  int t = threadIdx.x;
  int w = t >> 6, lane = t & 63;
  int m = lane & 15, quad = lane >> 4;

  const bf16* k1g0 = k1 + ((long)b * SDIM) * 1024 + kv * 128;
  const bf16* k2g0 = k2 + ((long)b * SDIM) * 1024 + kv * 128;
  const bf16* vtg0 = vT + ((long)(b * NKV + kv)) * 128 * 1024;

  int t0 = tile * 64;
  int i0w = t0 + w * 16;  // this wave's 16 query rows

  // load q0 and reconstruct roped q1 in-register
  const bf16* q0p = q0 + ((long)(b * SDIM + i0w + m)) * 2048 + h * 128 + quad * 8;
  bf16x8 q0f[4], q1f[4];
  int srow = i0w + m;
  for (int kc = 0; kc < 4; ++kc) {
    q0f[kc] = load8(q0p + kc * 32);
    for (int p4 = 0; p4 < 4; ++p4) {
      int dp = kc * 16 + quad * 4 + p4;
      float c = fc[srow * 64 + dp], sn = fs[srow * 64 + dp];
      float xr = (float)q0f[kc][2 * p4], xi = (float)q0f[kc][2 * p4 + 1];
      q1f[kc][2 * p4]     = (bf16)(xr * c - xi * sn);
      q1f[kc][2 * p4 + 1] = (bf16)(xr * sn + xi * c);
    }
  }

  // segment table: s < NS2 -> far (k2) at j0 = s*64 (last one partial); s >= NS2 -> window (k1).
  int NS2 = tile >= 4 ? tile - 3 : 0;
  int NSEG = NS2 + (tile < 4 ? tile + 1 : 5);
  int j1base = tile >= 4 ? t0 - 256 : 0;

  auto stage = [&](int s) {
    int j0, md;
    if (s < NS2) { j0 = s * 64; md = 2; } else { j0 = j1base + (s - NS2) * 64; md = 1; }
    const bf16* kg0 = (md == 1) ? k1g0 : k2g0;
    bf16* Kd = Kb[s & 1];
    bf16* Vd = Vb[s & 1];
    for (int p = 0; p < 4; ++p) {
      int idx = p * 256 + t;
      int kr = idx >> 4, kcs = idx & 15;
      int kg = (kcs ^ (kr & 15)) * 8;
      gl_lds16(&kg0[(long)(j0 + kr) * 1024 + kg], &Kd[idx * 8]);
      int vd = idx >> 3, vcs = idx & 7;
      int vg = (vcs ^ (vd & 7)) * 8;
      gl_lds16(&vtg0[(long)vd * 1024 + j0 + vg], &Vd[idx * 8]);
    }
  };

  f32x4 o[8] = {};
  float mrow = -INFINITY, lrow = 0.f;  // per-lane: row q = i0w + m
  int i = i0w + m;

  stage(0);
  for (int s = 0; s < NSEG; ++s) {
    if (s + 1 < NSEG) {
      stage(s + 1);
      asm volatile("s_waitcnt vmcnt(8)\n\ts_barrier" ::: "memory");  // seg s ready; s+1 in flight
    } else {
      asm volatile("s_waitcnt vmcnt(0)\n\ts_barrier" ::: "memory");
    }
    int j0, md;
    if (s < NS2) { j0 = s * 64; md = 2; } else { j0 = j1base + (s - NS2) * 64; md = 1; }
    bool fullseg = (md == 2) && (s < NS2 - 1);  // far block fully valid: no masking
    const bf16* Ks = Kb[s & 1];
    const bf16* VTs = Vb[s & 1];

    // QK^T (one branch per segment)
    f32x4 sc[4] = {};
    if (md == 1) {
      for (int st = 0; st < 4; ++st)
        for (int kc = 0; kc < 4; ++kc) {
          int cc = kc * 4 + quad;
          sc[st] = __builtin_amdgcn_mfma_f32_16x16x32_bf16(
              load8(&Ks[((st * 16 + m) * 16 + (cc ^ m)) * 8]), q1f[kc], sc[st], 0, 0, 0);
        }
    } else {
      for (int st = 0; st < 4; ++st)
        for (int kc = 0; kc < 4; ++kc) {
          int cc = kc * 4 + quad;
          sc[st] = __builtin_amdgcn_mfma_f32_16x16x32_bf16(
              load8(&Ks[((st * 16 + m) * 16 + (cc ^ m)) * 8]), q0f[kc], sc[st], 0, 0, 0);
        }
    }

    // mask
    float sv[4][4];
    for (int st = 0; st < 4; ++st)
      for (int r = 0; r < 4; ++r) {
        float v = sc[st][r];
        if (!fullseg) {
          int j = j0 + st * 16 + quad * 4 + r;
          if (md == 1) {
            if (j > i || j <= i - WINDOW) v = -INFINITY;
          } else {
            if (j > i - WINDOW) v = -INFINITY;
          }
        }
        sv[st][r] = v;
      }

    // online softmax
    float bm = -INFINITY;
    for (int st = 0; st < 4; ++st)
      for (int r = 0; r < 4; ++r) bm = fmaxf(bm, sv[st][r]);
    bm = fmaxf(bm, __shfl_xor(bm, 16, 64));
    bm = fmaxf(bm, __shfl_xor(bm, 32, 64));
    float mnew = fmaxf(mrow, bm);
    float rs = 0.f;
    for (int st = 0; st < 4; ++st) {
      bf16x4 pk;
      for (int r = 0; r < 4; ++r) {
        float pvv = exp2f((sv[st][r] - mnew) * L2E);
        rs += pvv;
        pk[r] = (bf16)pvv;
      }
      *(bf16x4*)&Pl[w][m][st * 16 + quad * 4] = pk;
    }
    rs += __shfl_xor(rs, 16, 64);
    rs += __shfl_xor(rs, 32, 64);
    if (__any(mnew > mrow)) {  // skip O-rescale when no row's max moved
      float alpha = exp2f((mrow - mnew) * L2E);
      lrow = lrow * alpha + rs;
      mrow = mnew;
      if (lane < 16) stats[w][lane] = alpha;
      f32x4 av = *(f32x4*)&stats[w][quad * 4];
      for (int n8 = 0; n8 < 8; ++n8)
        for (int r = 0; r < 4; ++r) o[n8][r] *= av[r];
    } else {
      lrow += rs;
    }

    // PV
    for (int kc = 0; kc < 2; ++kc) {
      bf16x8 af = load8(&Pl[w][m][kc * 32 + quad * 8]);
      int cc = kc * 4 + quad;
      for (int n8 = 0; n8 < 8; ++n8) {
        int d = n8 * 16 + m;
        o[n8] = __builtin_amdgcn_mfma_f32_16x16x32_bf16(
            af, load8(&VTs[(d * 8 + (cc ^ (d & 7))) * 8]), o[n8], 0, 0, 0);
      }
    }
    asm volatile("s_barrier" ::: "memory");  // all waves done reading buf before next overwrite
  }

  if (lane < 16) stats[w][lane] = lrow;
  __builtin_amdgcn_s_waitcnt(0);
  f32x4 lv = *(f32x4*)&stats[w][quad * 4];
  for (int n8 = 0; n8 < 8; ++n8)
    for (int r = 0; r < 4; ++r) {
      int row = i0w + quad * 4 + r;
      float val = o[n8][r] / lv[r];
      aout[((long)(b * SDIM + row)) * 2048 + h * 128 + n8 * 16 + m] = (bf16)val;
    }
}

extern "C" void kernel_launch(void* const* d_in, const int* in_sizes, int n_in,
                              void* d_out, int out_size, void* d_ws, size_t ws_size,
                              hipStream_t stream) {
  const float* x  = (const float*)d_in[0];
  const float* fc = (const float*)d_in[1];
  const float* fs = (const float*)d_in[2];
  const float* wq = (const float*)d_in[3];
  const float* wk = (const float*)d_in[4];
  const float* wv = (const float*)d_in[5];
  const float* wo = (const float*)d_in[6];
  float* out = (float*)d_out;

  // workspace layout (bf16 elements)
  bf16* wqkvT = (bf16*)d_ws;                  // [4096][2048]
  bf16* woT   = wqkvT + 4096L * 2048;         // [2048][2048]
  bf16* xb    = woT + 2048L * 2048;           // [2048][2048]
  bf16* q0b   = xb + 2048L * 2048;            // [2048][2048]
  bf16* k1b   = q0b + 2048L * 2048;           // [2048][1024]
  bf16* k2b   = k1b + 2048L * 1024;           // [2048][1024]
  bf16* vT    = k2b + 2048L * 1024;           // [16][128][1024]
  bf16* aout  = vT + 2048L * 1024;            // [2048][2048]

  prep<<<dim3(32, 32, 5), 256, 0, stream>>>(x, wq, wk, wv, wo, xb, wqkvT, woT);

  gemm_qkv<<<dim3(16, 16), 512, 0, stream>>>(xb, wqkvT, fc, fs, q0b, k1b, k2b, vT);

  attn_kernel<<<dim3(16, 16, 2), 256, 0, stream>>>(q0b, k1b, k2b, vT, fc, fs, aout);

  gemm_bt128<<<dim3(16, 16), 512, 0, stream>>>(aout, woT, out, 2048, 2048, 2048);
}

// Round 9
// 220.660 us; speedup vs baseline: 1.0163x; 1.0163x over previous
//
#include <hip/hip_runtime.h>
#include <hip/hip_bf16.h>

#define BDIM 2
#define SDIM 1024
#define DDIM 2048
#define NH 16
#define NKV 8
#define HD 128
#define WINDOW 256

typedef __bf16 bf16;
typedef __bf16 bf16x4 __attribute__((ext_vector_type(4)));
typedef __bf16 bf16x8 __attribute__((ext_vector_type(8)));
typedef float f32x4 __attribute__((ext_vector_type(4)));

#define L2E 1.44269504088896341f

__device__ inline bf16x8 load8(const bf16* p) { return *reinterpret_cast<const bf16x8*>(p); }

// async global->LDS, 16 B per lane (LDS dest = wave-uniform base + lane*16)
__device__ __forceinline__ void gl_lds16(const bf16* g, bf16* l) {
  __builtin_amdgcn_global_load_lds(
      (__attribute__((address_space(1))) void*)g,
      (__attribute__((address_space(3))) void*)l,
      16, 0, 0);
}

// ---------------- prep v2: vectorized weight transposes (z=0..3) + x cast (z=4) ----------------
__global__ __launch_bounds__(256) void prep(const float* __restrict__ x,
                                            const float* __restrict__ wq,
                                            const float* __restrict__ wk,
                                            const float* __restrict__ wv,
                                            const float* __restrict__ wo,
                                            bf16* __restrict__ xb,
                                            bf16* __restrict__ wqkvT,
                                            bf16* __restrict__ woT) {
  __shared__ bf16 tl[64][72];   // row stride 144B: 8B-aligned rows for bf16x4 ops
  int z = blockIdx.z;
  int t = threadIdx.x;
  if (z == 4) {  // cast x -> xb, 16 elems/thread, coalesced
    long base = ((long)(blockIdx.y * 32 + blockIdx.x)) * 4096;
    const float* xs = x + base;
    bf16* xo = xb + base;
#pragma unroll
    for (int e = 0; e < 4; ++e) {
      float4 a = *(const float4*)&xs[(e * 256 + t) * 4];
      bf16x4 o;
      o[0] = (bf16)a.x; o[1] = (bf16)a.y; o[2] = (bf16)a.z; o[3] = (bf16)a.w;
      *(bf16x4*)&xo[(e * 256 + t) * 4] = o;
    }
    return;
  }
  const float* src; bf16* dst; int C;
  if (z == 0)      { src = wq; dst = wqkvT;                 C = 2048; }
  else if (z == 1) { src = wk; dst = wqkvT + 2048L * 2048;  C = 1024; }
  else if (z == 2) { src = wv; dst = wqkvT + 3072L * 2048;  C = 1024; }
  else             { src = wo; dst = woT;                   C = 2048; }
  int c0 = blockIdx.x * 64, r0 = blockIdx.y * 64;
  if (c0 >= C) return;
  int tx = t & 15, ty = t >> 4;   // 16 x 16 thread layout
#pragma unroll
  for (int rr = 0; rr < 4; ++rr) {
    int row = ty + rr * 16;
    float4 a = *(const float4*)&src[(long)(r0 + row) * C + c0 + tx * 4];
    bf16x4 o;
    o[0] = (bf16)a.x; o[1] = (bf16)a.y; o[2] = (bf16)a.z; o[3] = (bf16)a.w;
    *(bf16x4*)&tl[row][tx * 4] = o;
  }
  __syncthreads();
#pragma unroll
  for (int rr = 0; rr < 4; ++rr) {
    int cc = ty + rr * 16;
    bf16x4 o;
#pragma unroll
    for (int e = 0; e < 4; ++e) o[e] = tl[tx * 4 + e][cc];
    *(bf16x4*)&dst[(long)(c0 + cc) * 2048 + r0 + tx * 4] = o;
  }
}

// ---------------- out-proj GEMM v2: 128x128 tiles, 8 waves, counted-vmcnt double-buffered ------
__global__ __launch_bounds__(512) void gemm_bt128(const bf16* __restrict__ A,
                                                  const bf16* __restrict__ Bt,
                                                  float* __restrict__ C,
                                                  int M, int N, int K) {
  __shared__ bf16 smem[2 * 16384];  // per buffer: As 128*64 + Bs 128*64 = 16384 elems = 32 KB
  int t = threadIdx.x;
  int wid = t >> 6, lane = t & 63;
  int wm = (wid >> 2) * 64, wn = (wid & 3) * 32;  // 2M x 4N waves, 64x32 per wave
  int fm = lane & 15, quad = lane >> 4;

  int wg = blockIdx.y * 16 + blockIdx.x;
  int swz = (wg & 7) * 32 + (wg >> 3);
  int by = swz >> 4, bx = swz & 15;
  int m0 = by * 128, n0 = bx * 128;

  const bf16* Ag = A + (long)m0 * K;
  const bf16* Bg = Bt + (long)n0 * K;

  f32x4 acc[4][2] = {};

  auto stA = [&](bf16* dst, int k0, int p) {
    int idx = p * 512 + t;
    int row = idx >> 3, ccs = idx & 7;
    int gcol = ((ccs ^ (row & 7)) * 8);
    gl_lds16(&Ag[(long)row * K + k0 + gcol], &dst[idx * 8]);
  };
  auto stB = [&](bf16* dst, int k0, int p) {
    int idx = p * 512 + t;
    int row = idx >> 3, ccs = idx & 7;
    int gcol = ((ccs ^ (row & 7)) * 8);
    gl_lds16(&Bg[(long)row * K + k0 + gcol], &dst[idx * 8]);
  };
  auto cmp = [&](const bf16* As, const bf16* Bs, int ks) {
    int cc = (ks >> 3) + quad;
    bf16x8 af[4], bfr[2];
    for (int i = 0; i < 4; ++i) {
      int fr = wm + i * 16 + fm;
      af[i] = load8(&As[(fr * 8 + (cc ^ (fr & 7))) * 8]);
    }
    for (int j = 0; j < 2; ++j) {
      int fr = wn + j * 16 + fm;
      bfr[j] = load8(&Bs[(fr * 8 + (cc ^ (fr & 7))) * 8]);
    }
    __builtin_amdgcn_s_setprio(1);
    for (int i = 0; i < 4; ++i)
      for (int j = 0; j < 2; ++j)
        acc[i][j] = __builtin_amdgcn_mfma_f32_16x16x32_bf16(af[i], bfr[j], acc[i][j], 0, 0, 0);
    __builtin_amdgcn_s_setprio(0);
  };

  {  // prologue: stage K-tile 0 (4 loads/thread)
    bf16* As = smem; bf16* Bs = smem + 8192;
    stA(As, 0, 0); stA(As, 0, 1);
    stB(Bs, 0, 0); stB(Bs, 0, 1);
  }
  const int NT = K / 64;
  for (int kt = 0; kt < NT; ++kt) {
    int cur = kt & 1;
    bf16* As = smem + cur * 16384;
    bf16* Bs = As + 8192;
    if (kt + 1 < NT) {
      bf16* An = smem + (cur ^ 1) * 16384;
      bf16* Bn = An + 8192;
      int kn = (kt + 1) * 64;
      stA(An, kn, 0); stB(Bn, kn, 0);
      asm volatile("s_waitcnt vmcnt(2)\n\ts_barrier" ::: "memory");
      cmp(As, Bs, 0);
      stA(An, kn, 1); stB(Bn, kn, 1);
      cmp(As, Bs, 32);
      asm volatile("s_barrier" ::: "memory");
    } else {
      asm volatile("s_waitcnt vmcnt(0)\n\ts_barrier" ::: "memory");
      cmp(As, Bs, 0);
      cmp(As, Bs, 32);
    }
  }
  for (int i = 0; i < 4; ++i)
    for (int r = 0; r < 4; ++r) {
      int row = m0 + wm + i * 16 + quad * 4 + r;
      for (int j = 0; j < 2; ++j) {
        int col = n0 + wn + j * 16 + fm;
        C[(long)row * N + col] = acc[i][j][r];
      }
    }
}

// ---------------- QKV GEMM, 128x256 tile, 8 waves, counted-vmcnt double-buffered ----------------
#define VPITCH 130
__global__ __launch_bounds__(512) void gemm_qkv(const bf16* __restrict__ A,
                                                const bf16* __restrict__ Bt,
                                                const float* __restrict__ fc,
                                                const float* __restrict__ fs,
                                                bf16* __restrict__ q0,
                                                bf16* __restrict__ k1,
                                                bf16* __restrict__ k2,
                                                bf16* __restrict__ vT) {
  const int K = 2048;
  __shared__ bf16 smem[2 * 24576];
  int t = threadIdx.x;
  int wid = t >> 6, lane = t & 63;
  int wm = (wid >> 2) * 64, wn = (wid & 3) * 64;
  int fm = lane & 15, quad = lane >> 4;

  int wg = blockIdx.y * 16 + blockIdx.x;
  int swz = (wg & 7) * 32 + (wg >> 3);
  int by = swz >> 4, bx = swz & 15;
  int m0 = by * 128, n0 = bx * 256;

  const bf16* Ag = A + (long)m0 * K;
  const bf16* Bg = Bt + (long)n0 * K;

  f32x4 acc[4][4] = {};

  auto stA = [&](bf16* dst, int k0, int p) {
    int idx = p * 512 + t;
    int row = idx >> 3, ccs = idx & 7;
    int gcol = ((ccs ^ (row & 7)) * 8);
    gl_lds16(&Ag[(long)row * K + k0 + gcol], &dst[idx * 8]);
  };
  auto stB = [&](bf16* dst, int k0, int p) {
    int idx = p * 512 + t;
    int row = idx >> 3, ccs = idx & 7;
    int gcol = ((ccs ^ (row & 7)) * 8);
    gl_lds16(&Bg[(long)row * K + k0 + gcol], &dst[idx * 8]);
  };
  auto cmp = [&](const bf16* As, const bf16* Bs, int ks) {
    int cc = (ks >> 3) + quad;
    bf16x8 af[4], bfr[4];
    for (int i = 0; i < 4; ++i) {
      int fr = wm + i * 16 + fm;
      af[i] = load8(&As[(fr * 8 + (cc ^ (fr & 7))) * 8]);
    }
    for (int j = 0; j < 4; ++j) {
      int fr = wn + j * 16 + fm;
      bfr[j] = load8(&Bs[(fr * 8 + (cc ^ (fr & 7))) * 8]);
    }
    __builtin_amdgcn_s_setprio(1);
    for (int i = 0; i < 4; ++i)
      for (int j = 0; j < 4; ++j)
        acc[i][j] = __builtin_amdgcn_mfma_f32_16x16x32_bf16(af[i], bfr[j], acc[i][j], 0, 0, 0);
    __builtin_amdgcn_s_setprio(0);
  };

  {
    bf16* As = smem; bf16* Bs = smem + 8192;
    stA(As, 0, 0); stA(As, 0, 1);
    stB(Bs, 0, 0); stB(Bs, 0, 1); stB(Bs, 0, 2); stB(Bs, 0, 3);
  }
  const int NT = K / 64;
  for (int kt = 0; kt < NT; ++kt) {
    int cur = kt & 1;
    bf16* As = smem + cur * 24576;
    bf16* Bs = As + 8192;
    if (kt + 1 < NT) {
      bf16* An = smem + (cur ^ 1) * 24576;
      bf16* Bn = An + 8192;
      int kn = (kt + 1) * 64;
      stA(An, kn, 0); stA(An, kn, 1); stB(Bn, kn, 0);
      asm volatile("s_waitcnt vmcnt(3)\n\ts_barrier" ::: "memory");
      cmp(As, Bs, 0);
      stB(Bn, kn, 1); stB(Bn, kn, 2); stB(Bn, kn, 3);
      cmp(As, Bs, 32);
      asm volatile("s_barrier" ::: "memory");
    } else {
      asm volatile("s_waitcnt vmcnt(0)\n\ts_barrier" ::: "memory");
      cmp(As, Bs, 0);
      cmp(As, Bs, 32);
    }
  }

  if (n0 < 2048) {  // ---- Q: raw scaled store (no rope)
    const float scale = 0.08838834764831845f;
    for (int i = 0; i < 4; ++i)
      for (int r = 0; r < 4; ++r) {
        int row = m0 + wm + i * 16 + quad * 4 + r;
        for (int j = 0; j < 4; ++j) {
          int gc = n0 + wn + j * 16 + fm;
          q0[(long)row * 2048 + gc] = (bf16)(acc[i][j][r] * scale);
        }
      }
  } else if (n0 < 3072) {  // ---- K: k1 = R(s)k, k2 = R(-W)k
    float sgn = (lane & 1) ? 1.f : -1.f;
    float cwj[4], swj[4];
    for (int j = 0; j < 4; ++j) {
      int dp = ((wn + j * 16 + fm) & 127) >> 1;
      cwj[j] = fc[WINDOW * 64 + dp];
      swj[j] = fs[WINDOW * 64 + dp] * (-sgn);
    }
    for (int i = 0; i < 4; ++i)
      for (int r = 0; r < 4; ++r) {
        int row = m0 + wm + i * 16 + quad * 4 + r;
        int s = row & (SDIM - 1);
        for (int j = 0; j < 4; ++j) {
          int kc = n0 - 2048 + wn + j * 16 + fm;
          int dp = (kc & 127) >> 1;
          float v = acc[i][j][r];
          float pp = __shfl_xor(v, 1, 64);
          float c = fc[s * 64 + dp];
          float sn = fs[s * 64 + dp] * sgn;
          long dst = (long)row * 1024 + kc;
          k1[dst] = (bf16)(v * c + pp * sn);
          k2[dst] = (bf16)(v * cwj[j] + pp * swj[j]);
        }
      }
  } else {  // ---- V: two 128-col halves through reused staging LDS
    int vv0 = (n0 - 3072) >> 7;
    int s0l = m0 & (SDIM - 1);
    int bq = m0 >> 10;
    for (int half = 0; half < 2; ++half) {
      __syncthreads();
      if (((wn >> 7) & 1) == half) {
        for (int i = 0; i < 4; ++i)
          for (int j = 0; j < 4; ++j) {
            int col = (wn & 127) + j * 16 + fm;
            for (int r = 0; r < 4; ++r) {
              int rl = wm + i * 16 + quad * 4 + r;
              smem[col * VPITCH + rl] = (bf16)acc[i][j][r];
            }
          }
      }
      __syncthreads();
      bf16* vtg = vT + ((long)(bq * NKV + vv0 + half)) * 128 * 1024;
      for (int p = 0; p < 4; ++p) {
        int c = p * 512 + t;
        int d = c >> 4, sc = (c & 15) * 8;
        *(bf16x8*)&vtg[(long)d * 1024 + s0l + sc] = *(bf16x8*)&smem[d * VPITCH + sc];
      }
    }
  }
}

// ---------------- Flash attention v13: v8 + defer-max (T13) + window-interior fullseg ---------
// v8 structure verbatim (48.3 us verified). Changes:
// (1) defer-max: P = exp2(s - m_old) immediately (no wait on the max-reduce); rescale only when
//     block max grew past m_old + 8 (rare). mrow init -30 (softmax shift-invariant).
// (2) fullseg extended to window-interior segments: j0 in [t0-192, t0-64] has all keys valid
//     for every row in the block (j <= i and j > i-256 hold for all i in [t0, t0+63]).
__global__ __launch_bounds__(256) void attn_kernel(const bf16* __restrict__ q0,
                                                   const bf16* __restrict__ k1,
                                                   const bf16* __restrict__ k2,
                                                   const bf16* __restrict__ vT,
                                                   const float* __restrict__ fc,
                                                   const float* __restrict__ fs,
                                                   bf16* __restrict__ aout) {
  __shared__ bf16 Kb[2][8192];   // [buf][64 key rows x 128 d] swizzled
  __shared__ bf16 Vb[2][8192];   // [buf][128 d x 64 keys] swizzled
  __shared__ bf16 Pl[4][16][72];
  __shared__ float stats[4][16];

  int h = blockIdx.y;
  int b = blockIdx.z;
  int tile = b ? (15 - blockIdx.x) : blockIdx.x;
  int kv = h >> 1;  // NREP = 2
  int t = threadIdx.x;
  int w = t >> 6, lane = t & 63;
  int m = lane & 15, quad = lane >> 4;

  const bf16* k1g0 = k1 + ((long)b * SDIM) * 1024 + kv * 128;
  const bf16* k2g0 = k2 + ((long)b * SDIM) * 1024 + kv * 128;
  const bf16* vtg0 = vT + ((long)(b * NKV + kv)) * 128 * 1024;

  int t0 = tile * 64;
  int i0w = t0 + w * 16;  // this wave's 16 query rows

  // load q0 and reconstruct roped q1 in-register
  const bf16* q0p = q0 + ((long)(b * SDIM + i0w + m)) * 2048 + h * 128 + quad * 8;
  bf16x8 q0f[4], q1f[4];
  int srow = i0w + m;
  for (int kc = 0; kc < 4; ++kc) {
    q0f[kc] = load8(q0p + kc * 32);
    for (int p4 = 0; p4 < 4; ++p4) {
      int dp = kc * 16 + quad * 4 + p4;
      float c = fc[srow * 64 + dp], sn = fs[srow * 64 + dp];
      float xr = (float)q0f[kc][2 * p4], xi = (float)q0f[kc][2 * p4 + 1];
      q1f[kc][2 * p4]     = (bf16)(xr * c - xi * sn);
      q1f[kc][2 * p4 + 1] = (bf16)(xr * sn + xi * c);
    }
  }

  // segment table: s < NS2 -> far (k2) at j0 = s*64 (last one partial); s >= NS2 -> window (k1).
  int NS2 = tile >= 4 ? tile - 3 : 0;
  int NSEG = NS2 + (tile < 4 ? tile + 1 : 5);
  int j1base = tile >= 4 ? t0 - 256 : 0;

  auto stage = [&](int s) {
    int j0, md;
    if (s < NS2) { j0 = s * 64; md = 2; } else { j0 = j1base + (s - NS2) * 64; md = 1; }
    const bf16* kg0 = (md == 1) ? k1g0 : k2g0;
    bf16* Kd = Kb[s & 1];
    bf16* Vd = Vb[s & 1];
    for (int p = 0; p < 4; ++p) {
      int idx = p * 256 + t;
      int kr = idx >> 4, kcs = idx & 15;
      int kg = (kcs ^ (kr & 15)) * 8;
      gl_lds16(&kg0[(long)(j0 + kr) * 1024 + kg], &Kd[idx * 8]);
      int vd = idx >> 3, vcs = idx & 7;
      int vg = (vcs ^ (vd & 7)) * 8;
      gl_lds16(&vtg0[(long)vd * 1024 + j0 + vg], &Vd[idx * 8]);
    }
  };

  f32x4 o[8] = {};
  float mrow = -30.f, lrow = 0.f;  // finite init for defer-max (softmax shift-invariant)
  int i = i0w + m;

  stage(0);
  for (int s = 0; s < NSEG; ++s) {
    if (s + 1 < NSEG) {
      stage(s + 1);
      asm volatile("s_waitcnt vmcnt(8)\n\ts_barrier" ::: "memory");  // seg s ready; s+1 in flight
    } else {
      asm volatile("s_waitcnt vmcnt(0)\n\ts_barrier" ::: "memory");
    }
    int j0, md;
    if (s < NS2) { j0 = s * 64; md = 2; } else { j0 = j1base + (s - NS2) * 64; md = 1; }
    // fullseg: far interior OR window interior (all keys valid for every row in the block)
    bool fullseg = (md == 2) ? (s < NS2 - 1)
                             : (j0 >= t0 - 192 && j0 <= t0 - 64);
    const bf16* Ks = Kb[s & 1];
    const bf16* VTs = Vb[s & 1];

    // QK^T (one branch per segment)
    f32x4 sc[4] = {};
    if (md == 1) {
      for (int st = 0; st < 4; ++st)
        for (int kc = 0; kc < 4; ++kc) {
          int cc = kc * 4 + quad;
          sc[st] = __builtin_amdgcn_mfma_f32_16x16x32_bf16(
              load8(&Ks[((st * 16 + m) * 16 + (cc ^ m)) * 8]), q1f[kc], sc[st], 0, 0, 0);
        }
    } else {
      for (int st = 0; st < 4; ++st)
        for (int kc = 0; kc < 4; ++kc) {
          int cc = kc * 4 + quad;
          sc[st] = __builtin_amdgcn_mfma_f32_16x16x32_bf16(
              load8(&Ks[((st * 16 + m) * 16 + (cc ^ m)) * 8]), q0f[kc], sc[st], 0, 0, 0);
        }
    }

    // mask
    float sv[4][4];
    for (int st = 0; st < 4; ++st)
      for (int r = 0; r < 4; ++r) {
        float v = sc[st][r];
        if (!fullseg) {
          int j = j0 + st * 16 + quad * 4 + r;
          if (md == 1) {
            if (j > i || j <= i - WINDOW) v = -INFINITY;
          } else {
            if (j > i - WINDOW) v = -INFINITY;
          }
        }
        sv[st][r] = v;
      }

    // defer-max softmax (T13): exp with OLD mrow immediately; max-reduce runs in parallel
    float pv[4][4];
    for (int st = 0; st < 4; ++st)
      for (int r = 0; r < 4; ++r)
        pv[st][r] = exp2f((sv[st][r] - mrow) * L2E);
    float bm = -INFINITY;
    for (int st = 0; st < 4; ++st)
      for (int r = 0; r < 4; ++r) bm = fmaxf(bm, sv[st][r]);
    bm = fmaxf(bm, __shfl_xor(bm, 16, 64));
    bm = fmaxf(bm, __shfl_xor(bm, 32, 64));
    if (!__all(bm <= mrow + 8.f)) {  // rare: max grew past tolerance -> rescale
      float mnew = fmaxf(mrow, bm);
      float alpha = exp2f((mrow - mnew) * L2E);
      for (int st = 0; st < 4; ++st)
        for (int r = 0; r < 4; ++r) pv[st][r] *= alpha;
      lrow *= alpha;
      if (lane < 16) stats[w][lane] = alpha;
      f32x4 av = *(f32x4*)&stats[w][quad * 4];
      for (int n8 = 0; n8 < 8; ++n8)
        for (int r = 0; r < 4; ++r) o[n8][r] *= av[r];
      mrow = mnew;
    }
    float rs = 0.f;
    for (int st = 0; st < 4; ++st) {
      bf16x4 pk;
      for (int r = 0; r < 4; ++r) {
        rs += pv[st][r];
        pk[r] = (bf16)pv[st][r];
      }
      *(bf16x4*)&Pl[w][m][st * 16 + quad * 4] = pk;
    }
    rs += __shfl_xor(rs, 16, 64);
    rs += __shfl_xor(rs, 32, 64);
    lrow += rs;

    // PV
    for (int kc = 0; kc < 2; ++kc) {
      bf16x8 af = load8(&Pl[w][m][kc * 32 + quad * 8]);
      int cc = kc * 4 + quad;
      for (int n8 = 0; n8 < 8; ++n8) {
        int d = n8 * 16 + m;
        o[n8] = __builtin_amdgcn_mfma_f32_16x16x32_bf16(
            af, load8(&VTs[(d * 8 + (cc ^ (d & 7))) * 8]), o[n8], 0, 0, 0);
      }
    }
    asm volatile("s_barrier" ::: "memory");  // all waves done reading buf before next overwrite
  }

  if (lane < 16) stats[w][lane] = lrow;
  __builtin_amdgcn_s_waitcnt(0);
  f32x4 lv = *(f32x4*)&stats[w][quad * 4];
  for (int n8 = 0; n8 < 8; ++n8)
    for (int r = 0; r < 4; ++r) {
      int row = i0w + quad * 4 + r;
      float val = o[n8][r] / lv[r];
      aout[((long)(b * SDIM + row)) * 2048 + h * 128 + n8 * 16 + m] = (bf16)val;
    }
}

extern "C" void kernel_launch(void* const* d_in, const int* in_sizes, int n_in,
                              void* d_out, int out_size, void* d_ws, size_t ws_size,
                              hipStream_t stream) {
  const float* x  = (const float*)d_in[0];
  const float* fc = (const float*)d_in[1];
  const float* fs = (const float*)d_in[2];
  const float* wq = (const float*)d_in[3];
  const float* wk = (const float*)d_in[4];
  const float* wv = (const float*)d_in[5];
  const float* wo = (const float*)d_in[6];
  float* out = (float*)d_out;

  // workspace layout (bf16 elements)
  bf16* wqkvT = (bf16*)d_ws;                  // [4096][2048]
  bf16* woT   = wqkvT + 4096L * 2048;         // [2048][2048]
  bf16* xb    = woT + 2048L * 2048;           // [2048][2048]
  bf16* q0b   = xb + 2048L * 2048;            // [2048][2048]
  bf16* k1b   = q0b + 2048L * 2048;           // [2048][1024]
  bf16* k2b   = k1b + 2048L * 1024;           // [2048][1024]
  bf16* vT    = k2b + 2048L * 1024;           // [16][128][1024]
  bf16* aout  = vT + 2048L * 1024;            // [2048][2048]

  prep<<<dim3(32, 32, 5), 256, 0, stream>>>(x, wq, wk, wv, wo, xb, wqkvT, woT);

  gemm_qkv<<<dim3(16, 16), 512, 0, stream>>>(xb, wqkvT, fc, fs, q0b, k1b, k2b, vT);

  attn_kernel<<<dim3(16, 16, 2), 256, 0, stream>>>(q0b, k1b, k2b, vT, fc, fs, aout);

  gemm_bt128<<<dim3(16, 16), 512, 0, stream>>>(aout, woT, out, 2048, 2048, 2048);
}

// Round 10
// 216.763 us; speedup vs baseline: 1.0345x; 1.0180x over previous
//
#include <hip/hip_runtime.h>
#include <hip/hip_bf16.h>

#define BDIM 2
#define SDIM 1024
#define DDIM 2048
#define NH 16
#define NKV 8
#define HD 128
#define WINDOW 256

typedef __bf16 bf16;
typedef __bf16 bf16x4 __attribute__((ext_vector_type(4)));
typedef __bf16 bf16x8 __attribute__((ext_vector_type(8)));
typedef float f32x4 __attribute__((ext_vector_type(4)));

#define L2E 1.44269504088896341f

__device__ inline bf16x8 load8(const bf16* p) { return *reinterpret_cast<const bf16x8*>(p); }

// async global->LDS, 16 B per lane (LDS dest = wave-uniform base + lane*16)
__device__ __forceinline__ void gl_lds16(const bf16* g, bf16* l) {
  __builtin_amdgcn_global_load_lds(
      (__attribute__((address_space(1))) void*)g,
      (__attribute__((address_space(3))) void*)l,
      16, 0, 0);
}

// ---------------- prep v2: vectorized weight transposes (z=0..3) + x cast (z=4) ----------------
__global__ __launch_bounds__(256) void prep(const float* __restrict__ x,
                                            const float* __restrict__ wq,
                                            const float* __restrict__ wk,
                                            const float* __restrict__ wv,
                                            const float* __restrict__ wo,
                                            bf16* __restrict__ xb,
                                            bf16* __restrict__ wqkvT,
                                            bf16* __restrict__ woT) {
  __shared__ bf16 tl[64][72];   // row stride 144B: 8B-aligned rows for bf16x4 ops
  int z = blockIdx.z;
  int t = threadIdx.x;
  if (z == 4) {  // cast x -> xb, 16 elems/thread, coalesced
    long base = ((long)(blockIdx.y * 32 + blockIdx.x)) * 4096;
    const float* xs = x + base;
    bf16* xo = xb + base;
#pragma unroll
    for (int e = 0; e < 4; ++e) {
      float4 a = *(const float4*)&xs[(e * 256 + t) * 4];
      bf16x4 o;
      o[0] = (bf16)a.x; o[1] = (bf16)a.y; o[2] = (bf16)a.z; o[3] = (bf16)a.w;
      *(bf16x4*)&xo[(e * 256 + t) * 4] = o;
    }
    return;
  }
  const float* src; bf16* dst; int C;
  if (z == 0)      { src = wq; dst = wqkvT;                 C = 2048; }
  else if (z == 1) { src = wk; dst = wqkvT + 2048L * 2048;  C = 1024; }
  else if (z == 2) { src = wv; dst = wqkvT + 3072L * 2048;  C = 1024; }
  else             { src = wo; dst = woT;                   C = 2048; }
  int c0 = blockIdx.x * 64, r0 = blockIdx.y * 64;
  if (c0 >= C) return;
  int tx = t & 15, ty = t >> 4;   // 16 x 16 thread layout
#pragma unroll
  for (int rr = 0; rr < 4; ++rr) {
    int row = ty + rr * 16;
    float4 a = *(const float4*)&src[(long)(r0 + row) * C + c0 + tx * 4];
    bf16x4 o;
    o[0] = (bf16)a.x; o[1] = (bf16)a.y; o[2] = (bf16)a.z; o[3] = (bf16)a.w;
    *(bf16x4*)&tl[row][tx * 4] = o;
  }
  __syncthreads();
#pragma unroll
  for (int rr = 0; rr < 4; ++rr) {
    int cc = ty + rr * 16;
    bf16x4 o;
#pragma unroll
    for (int e = 0; e < 4; ++e) o[e] = tl[tx * 4 + e][cc];
    *(bf16x4*)&dst[(long)(c0 + cc) * 2048 + r0 + tx * 4] = o;
  }
}

// ---------------- out-proj GEMM v2: 128x128 tiles, 8 waves, counted-vmcnt double-buffered ------
__global__ __launch_bounds__(512) void gemm_bt128(const bf16* __restrict__ A,
                                                  const bf16* __restrict__ Bt,
                                                  float* __restrict__ C,
                                                  int M, int N, int K) {
  __shared__ bf16 smem[2 * 16384];  // per buffer: As 128*64 + Bs 128*64 = 16384 elems = 32 KB
  int t = threadIdx.x;
  int wid = t >> 6, lane = t & 63;
  int wm = (wid >> 2) * 64, wn = (wid & 3) * 32;  // 2M x 4N waves, 64x32 per wave
  int fm = lane & 15, quad = lane >> 4;

  int wg = blockIdx.y * 16 + blockIdx.x;
  int swz = (wg & 7) * 32 + (wg >> 3);
  int by = swz >> 4, bx = swz & 15;
  int m0 = by * 128, n0 = bx * 128;

  const bf16* Ag = A + (long)m0 * K;
  const bf16* Bg = Bt + (long)n0 * K;

  f32x4 acc[4][2] = {};

  auto stA = [&](bf16* dst, int k0, int p) {
    int idx = p * 512 + t;
    int row = idx >> 3, ccs = idx & 7;
    int gcol = ((ccs ^ (row & 7)) * 8);
    gl_lds16(&Ag[(long)row * K + k0 + gcol], &dst[idx * 8]);
  };
  auto stB = [&](bf16* dst, int k0, int p) {
    int idx = p * 512 + t;
    int row = idx >> 3, ccs = idx & 7;
    int gcol = ((ccs ^ (row & 7)) * 8);
    gl_lds16(&Bg[(long)row * K + k0 + gcol], &dst[idx * 8]);
  };
  auto cmp = [&](const bf16* As, const bf16* Bs, int ks) {
    int cc = (ks >> 3) + quad;
    bf16x8 af[4], bfr[2];
    for (int i = 0; i < 4; ++i) {
      int fr = wm + i * 16 + fm;
      af[i] = load8(&As[(fr * 8 + (cc ^ (fr & 7))) * 8]);
    }
    for (int j = 0; j < 2; ++j) {
      int fr = wn + j * 16 + fm;
      bfr[j] = load8(&Bs[(fr * 8 + (cc ^ (fr & 7))) * 8]);
    }
    __builtin_amdgcn_s_setprio(1);
    for (int i = 0; i < 4; ++i)
      for (int j = 0; j < 2; ++j)
        acc[i][j] = __builtin_amdgcn_mfma_f32_16x16x32_bf16(af[i], bfr[j], acc[i][j], 0, 0, 0);
    __builtin_amdgcn_s_setprio(0);
  };

  {  // prologue: stage K-tile 0 (4 loads/thread)
    bf16* As = smem; bf16* Bs = smem + 8192;
    stA(As, 0, 0); stA(As, 0, 1);
    stB(Bs, 0, 0); stB(Bs, 0, 1);
  }
  const int NT = K / 64;
  for (int kt = 0; kt < NT; ++kt) {
    int cur = kt & 1;
    bf16* As = smem + cur * 16384;
    bf16* Bs = As + 8192;
    if (kt + 1 < NT) {
      bf16* An = smem + (cur ^ 1) * 16384;
      bf16* Bn = An + 8192;
      int kn = (kt + 1) * 64;
      stA(An, kn, 0); stB(Bn, kn, 0);
      asm volatile("s_waitcnt vmcnt(2)\n\ts_barrier" ::: "memory");
      cmp(As, Bs, 0);
      stA(An, kn, 1); stB(Bn, kn, 1);
      cmp(As, Bs, 32);
      asm volatile("s_barrier" ::: "memory");
    } else {
      asm volatile("s_waitcnt vmcnt(0)\n\ts_barrier" ::: "memory");
      cmp(As, Bs, 0);
      cmp(As, Bs, 32);
    }
  }
  for (int i = 0; i < 4; ++i)
    for (int r = 0; r < 4; ++r) {
      int row = m0 + wm + i * 16 + quad * 4 + r;
      for (int j = 0; j < 2; ++j) {
        int col = n0 + wn + j * 16 + fm;
        C[(long)row * N + col] = acc[i][j][r];
      }
    }
}

// ---------------- QKV GEMM v3: 128x256 tile, 3-buffer ring, depth-2 prefetch, 1 barrier/step ---
// qkv is staging-BW-bound (96KB/K-step/CU from L2 vs ~310cy of MFMA). Ring-3 (144KB LDS, still
// 1 block/CU) keeps the L2 pipe continuously fed: 12 loads outstanding entering each iter;
// per iter: wait vmcnt(6) [own stage-k landed] -> s_barrier [all waves: stage-k visible AND all
// finished reading slot (k-1)%3] -> stage(k+2) into slot (k+2)%3 == (k-1)%3 [safe] -> compute.
#define VPITCH 130
__global__ __launch_bounds__(512) void gemm_qkv(const bf16* __restrict__ A,
                                                const bf16* __restrict__ Bt,
                                                const float* __restrict__ fc,
                                                const float* __restrict__ fs,
                                                bf16* __restrict__ q0,
                                                bf16* __restrict__ k1,
                                                bf16* __restrict__ k2,
                                                bf16* __restrict__ vT) {
  const int K = 2048;
  __shared__ bf16 smem[3 * 24576];  // ring: per stage As 128*64 (8192) + Bs 256*64 (16384)
  int t = threadIdx.x;
  int wid = t >> 6, lane = t & 63;
  int wm = (wid >> 2) * 64, wn = (wid & 3) * 64;
  int fm = lane & 15, quad = lane >> 4;

  int wg = blockIdx.y * 16 + blockIdx.x;
  int swz = (wg & 7) * 32 + (wg >> 3);
  int by = swz >> 4, bx = swz & 15;
  int m0 = by * 128, n0 = bx * 256;

  const bf16* Ag = A + (long)m0 * K;
  const bf16* Bg = Bt + (long)n0 * K;

  f32x4 acc[4][4] = {};

  auto stage = [&](int kt) {  // 6 loads/thread: full A-tile + B-tile for K-step kt
    bf16* As = smem + (kt % 3) * 24576;
    bf16* Bs = As + 8192;
    int k0 = kt * 64;
    {
      int idx = t;                     // A rows 0..63
      int row = idx >> 3, ccs = idx & 7;
      gl_lds16(&Ag[(long)row * K + k0 + ((ccs ^ (row & 7)) * 8)], &As[idx * 8]);
      idx = 512 + t;                   // A rows 64..127
      row = idx >> 3; ccs = idx & 7;
      gl_lds16(&Ag[(long)row * K + k0 + ((ccs ^ (row & 7)) * 8)], &As[idx * 8]);
    }
#pragma unroll
    for (int p = 0; p < 4; ++p) {
      int idx = p * 512 + t;
      int row = idx >> 3, ccs = idx & 7;
      gl_lds16(&Bg[(long)row * K + k0 + ((ccs ^ (row & 7)) * 8)], &Bs[idx * 8]);
    }
  };
  auto cmp = [&](const bf16* As, const bf16* Bs, int ks) {
    int cc = (ks >> 3) + quad;
    bf16x8 af[4], bfr[4];
    for (int i = 0; i < 4; ++i) {
      int fr = wm + i * 16 + fm;
      af[i] = load8(&As[(fr * 8 + (cc ^ (fr & 7))) * 8]);
    }
    for (int j = 0; j < 4; ++j) {
      int fr = wn + j * 16 + fm;
      bfr[j] = load8(&Bs[(fr * 8 + (cc ^ (fr & 7))) * 8]);
    }
    __builtin_amdgcn_s_setprio(1);
    for (int i = 0; i < 4; ++i)
      for (int j = 0; j < 4; ++j)
        acc[i][j] = __builtin_amdgcn_mfma_f32_16x16x32_bf16(af[i], bfr[j], acc[i][j], 0, 0, 0);
    __builtin_amdgcn_s_setprio(0);
  };

  const int NT = K / 64;  // 32
  stage(0);
  stage(1);               // 12 outstanding
  for (int kt = 0; kt < NT; ++kt) {
    if (kt + 1 < NT) {
      asm volatile("s_waitcnt vmcnt(6)" ::: "memory");   // own stage-kt landed; kt+1 in flight
    } else {
      asm volatile("s_waitcnt vmcnt(0)" ::: "memory");
    }
    __builtin_amdgcn_s_barrier();  // all waves: stage-kt visible; all done reading slot (kt-1)%3
    if (kt + 2 < NT) stage(kt + 2);  // slot (kt+2)%3 == (kt-1)%3: free per barrier
    bf16* As = smem + (kt % 3) * 24576;
    bf16* Bs = As + 8192;
    cmp(As, Bs, 0);
    cmp(As, Bs, 32);
  }

  if (n0 < 2048) {  // ---- Q: raw scaled store (no rope)
    const float scale = 0.08838834764831845f;
    for (int i = 0; i < 4; ++i)
      for (int r = 0; r < 4; ++r) {
        int row = m0 + wm + i * 16 + quad * 4 + r;
        for (int j = 0; j < 4; ++j) {
          int gc = n0 + wn + j * 16 + fm;
          q0[(long)row * 2048 + gc] = (bf16)(acc[i][j][r] * scale);
        }
      }
  } else if (n0 < 3072) {  // ---- K: k1 = R(s)k, k2 = R(-W)k
    float sgn = (lane & 1) ? 1.f : -1.f;
    float cwj[4], swj[4];
    for (int j = 0; j < 4; ++j) {
      int dp = ((wn + j * 16 + fm) & 127) >> 1;
      cwj[j] = fc[WINDOW * 64 + dp];
      swj[j] = fs[WINDOW * 64 + dp] * (-sgn);
    }
    for (int i = 0; i < 4; ++i)
      for (int r = 0; r < 4; ++r) {
        int row = m0 + wm + i * 16 + quad * 4 + r;
        int s = row & (SDIM - 1);
        for (int j = 0; j < 4; ++j) {
          int kc = n0 - 2048 + wn + j * 16 + fm;
          int dp = (kc & 127) >> 1;
          float v = acc[i][j][r];
          float pp = __shfl_xor(v, 1, 64);
          float c = fc[s * 64 + dp];
          float sn = fs[s * 64 + dp] * sgn;
          long dst = (long)row * 1024 + kc;
          k1[dst] = (bf16)(v * c + pp * sn);
          k2[dst] = (bf16)(v * cwj[j] + pp * swj[j]);
        }
      }
  } else {  // ---- V: two 128-col halves through reused staging LDS
    int vv0 = (n0 - 3072) >> 7;
    int s0l = m0 & (SDIM - 1);
    int bq = m0 >> 10;
    for (int half = 0; half < 2; ++half) {
      __syncthreads();
      if (((wn >> 7) & 1) == half) {
        for (int i = 0; i < 4; ++i)
          for (int j = 0; j < 4; ++j) {
            int col = (wn & 127) + j * 16 + fm;
            for (int r = 0; r < 4; ++r) {
              int rl = wm + i * 16 + quad * 4 + r;
              smem[col * VPITCH + rl] = (bf16)acc[i][j][r];
            }
          }
      }
      __syncthreads();
      bf16* vtg = vT + ((long)(bq * NKV + vv0 + half)) * 128 * 1024;
      for (int p = 0; p < 4; ++p) {
        int c = p * 512 + t;
        int d = c >> 4, sc = (c & 15) * 8;
        *(bf16x8*)&vtg[(long)d * 1024 + s0l + sc] = *(bf16x8*)&smem[d * VPITCH + sc];
      }
    }
  }
}

// ---------------- Flash attention v13 (verified: attn off top-5 at 220.7 total) ----------------
__global__ __launch_bounds__(256) void attn_kernel(const bf16* __restrict__ q0,
                                                   const bf16* __restrict__ k1,
                                                   const bf16* __restrict__ k2,
                                                   const bf16* __restrict__ vT,
                                                   const float* __restrict__ fc,
                                                   const float* __restrict__ fs,
                                                   bf16* __restrict__ aout) {
  __shared__ bf16 Kb[2][8192];   // [buf][64 key rows x 128 d] swizzled
  __shared__ bf16 Vb[2][8192];   // [buf][128 d x 64 keys] swizzled
  __shared__ bf16 Pl[4][16][72];
  __shared__ float stats[4][16];

  int h = blockIdx.y;
  int b = blockIdx.z;
  int tile = b ? (15 - blockIdx.x) : blockIdx.x;
  int kv = h >> 1;  // NREP = 2
  int t = threadIdx.x;
  int w = t >> 6, lane = t & 63;
  int m = lane & 15, quad = lane >> 4;

  const bf16* k1g0 = k1 + ((long)b * SDIM) * 1024 + kv * 128;
  const bf16* k2g0 = k2 + ((long)b * SDIM) * 1024 + kv * 128;
  const bf16* vtg0 = vT + ((long)(b * NKV + kv)) * 128 * 1024;

  int t0 = tile * 64;
  int i0w = t0 + w * 16;  // this wave's 16 query rows

  // load q0 and reconstruct roped q1 in-register
  const bf16* q0p = q0 + ((long)(b * SDIM + i0w + m)) * 2048 + h * 128 + quad * 8;
  bf16x8 q0f[4], q1f[4];
  int srow = i0w + m;
  for (int kc = 0; kc < 4; ++kc) {
    q0f[kc] = load8(q0p + kc * 32);
    for (int p4 = 0; p4 < 4; ++p4) {
      int dp = kc * 16 + quad * 4 + p4;
      float c = fc[srow * 64 + dp], sn = fs[srow * 64 + dp];
      float xr = (float)q0f[kc][2 * p4], xi = (float)q0f[kc][2 * p4 + 1];
      q1f[kc][2 * p4]     = (bf16)(xr * c - xi * sn);
      q1f[kc][2 * p4 + 1] = (bf16)(xr * sn + xi * c);
    }
  }

  // segment table: s < NS2 -> far (k2) at j0 = s*64 (last one partial); s >= NS2 -> window (k1).
  int NS2 = tile >= 4 ? tile - 3 : 0;
  int NSEG = NS2 + (tile < 4 ? tile + 1 : 5);
  int j1base = tile >= 4 ? t0 - 256 : 0;

  auto stage = [&](int s) {
    int j0, md;
    if (s < NS2) { j0 = s * 64; md = 2; } else { j0 = j1base + (s - NS2) * 64; md = 1; }
    const bf16* kg0 = (md == 1) ? k1g0 : k2g0;
    bf16* Kd = Kb[s & 1];
    bf16* Vd = Vb[s & 1];
    for (int p = 0; p < 4; ++p) {
      int idx = p * 256 + t;
      int kr = idx >> 4, kcs = idx & 15;
      int kg = (kcs ^ (kr & 15)) * 8;
      gl_lds16(&kg0[(long)(j0 + kr) * 1024 + kg], &Kd[idx * 8]);
      int vd = idx >> 3, vcs = idx & 7;
      int vg = (vcs ^ (vd & 7)) * 8;
      gl_lds16(&vtg0[(long)vd * 1024 + j0 + vg], &Vd[idx * 8]);
    }
  };

  f32x4 o[8] = {};
  float mrow = -30.f, lrow = 0.f;  // finite init for defer-max (softmax shift-invariant)
  int i = i0w + m;

  stage(0);
  for (int s = 0; s < NSEG; ++s) {
    if (s + 1 < NSEG) {
      stage(s + 1);
      asm volatile("s_waitcnt vmcnt(8)\n\ts_barrier" ::: "memory");  // seg s ready; s+1 in flight
    } else {
      asm volatile("s_waitcnt vmcnt(0)\n\ts_barrier" ::: "memory");
    }
    int j0, md;
    if (s < NS2) { j0 = s * 64; md = 2; } else { j0 = j1base + (s - NS2) * 64; md = 1; }
    // fullseg: far interior OR window interior (all keys valid for every row in the block)
    bool fullseg = (md == 2) ? (s < NS2 - 1)
                             : (j0 >= t0 - 192 && j0 <= t0 - 64);
    const bf16* Ks = Kb[s & 1];
    const bf16* VTs = Vb[s & 1];

    // QK^T (one branch per segment)
    f32x4 sc[4] = {};
    if (md == 1) {
      for (int st = 0; st < 4; ++st)
        for (int kc = 0; kc < 4; ++kc) {
          int cc = kc * 4 + quad;
          sc[st] = __builtin_amdgcn_mfma_f32_16x16x32_bf16(
              load8(&Ks[((st * 16 + m) * 16 + (cc ^ m)) * 8]), q1f[kc], sc[st], 0, 0, 0);
        }
    } else {
      for (int st = 0; st < 4; ++st)
        for (int kc = 0; kc < 4; ++kc) {
          int cc = kc * 4 + quad;
          sc[st] = __builtin_amdgcn_mfma_f32_16x16x32_bf16(
              load8(&Ks[((st * 16 + m) * 16 + (cc ^ m)) * 8]), q0f[kc], sc[st], 0, 0, 0);
        }
    }

    // mask
    float sv[4][4];
    for (int st = 0; st < 4; ++st)
      for (int r = 0; r < 4; ++r) {
        float v = sc[st][r];
        if (!fullseg) {
          int j = j0 + st * 16 + quad * 4 + r;
          if (md == 1) {
            if (j > i || j <= i - WINDOW) v = -INFINITY;
          } else {
            if (j > i - WINDOW) v = -INFINITY;
          }
        }
        sv[st][r] = v;
      }

    // defer-max softmax (T13): exp with OLD mrow immediately; max-reduce runs in parallel
    float pv[4][4];
    for (int st = 0; st < 4; ++st)
      for (int r = 0; r < 4; ++r)
        pv[st][r] = exp2f((sv[st][r] - mrow) * L2E);
    float bm = -INFINITY;
    for (int st = 0; st < 4; ++st)
      for (int r = 0; r < 4; ++r) bm = fmaxf(bm, sv[st][r]);
    bm = fmaxf(bm, __shfl_xor(bm, 16, 64));
    bm = fmaxf(bm, __shfl_xor(bm, 32, 64));
    if (!__all(bm <= mrow + 8.f)) {  // rare: max grew past tolerance -> rescale
      float mnew = fmaxf(mrow, bm);
      float alpha = exp2f((mrow - mnew) * L2E);
      for (int st = 0; st < 4; ++st)
        for (int r = 0; r < 4; ++r) pv[st][r] *= alpha;
      lrow *= alpha;
      if (lane < 16) stats[w][lane] = alpha;
      f32x4 av = *(f32x4*)&stats[w][quad * 4];
      for (int n8 = 0; n8 < 8; ++n8)
        for (int r = 0; r < 4; ++r) o[n8][r] *= av[r];
      mrow = mnew;
    }
    float rs = 0.f;
    for (int st = 0; st < 4; ++st) {
      bf16x4 pk;
      for (int r = 0; r < 4; ++r) {
        rs += pv[st][r];
        pk[r] = (bf16)pv[st][r];
      }
      *(bf16x4*)&Pl[w][m][st * 16 + quad * 4] = pk;
    }
    rs += __shfl_xor(rs, 16, 64);
    rs += __shfl_xor(rs, 32, 64);
    lrow += rs;

    // PV
    for (int kc = 0; kc < 2; ++kc) {
      bf16x8 af = load8(&Pl[w][m][kc * 32 + quad * 8]);
      int cc = kc * 4 + quad;
      for (int n8 = 0; n8 < 8; ++n8) {
        int d = n8 * 16 + m;
        o[n8] = __builtin_amdgcn_mfma_f32_16x16x32_bf16(
            af, load8(&VTs[(d * 8 + (cc ^ (d & 7))) * 8]), o[n8], 0, 0, 0);
      }
    }
    asm volatile("s_barrier" ::: "memory");  // all waves done reading buf before next overwrite
  }

  if (lane < 16) stats[w][lane] = lrow;
  __builtin_amdgcn_s_waitcnt(0);
  f32x4 lv = *(f32x4*)&stats[w][quad * 4];
  for (int n8 = 0; n8 < 8; ++n8)
    for (int r = 0; r < 4; ++r) {
      int row = i0w + quad * 4 + r;
      float val = o[n8][r] / lv[r];
      aout[((long)(b * SDIM + row)) * 2048 + h * 128 + n8 * 16 + m] = (bf16)val;
    }
}

extern "C" void kernel_launch(void* const* d_in, const int* in_sizes, int n_in,
                              void* d_out, int out_size, void* d_ws, size_t ws_size,
                              hipStream_t stream) {
  const float* x  = (const float*)d_in[0];
  const float* fc = (const float*)d_in[1];
  const float* fs = (const float*)d_in[2];
  const float* wq = (const float*)d_in[3];
  const float* wk = (const float*)d_in[4];
  const float* wv = (const float*)d_in[5];
  const float* wo = (const float*)d_in[6];
  float* out = (float*)d_out;

  // workspace layout (bf16 elements)
  bf16* wqkvT = (bf16*)d_ws;                  // [4096][2048]
  bf16* woT   = wqkvT + 4096L * 2048;         // [2048][2048]
  bf16* xb    = woT + 2048L * 2048;           // [2048][2048]
  bf16* q0b   = xb + 2048L * 2048;            // [2048][2048]
  bf16* k1b   = q0b + 2048L * 2048;           // [2048][1024]
  bf16* k2b   = k1b + 2048L * 1024;           // [2048][1024]
  bf16* vT    = k2b + 2048L * 1024;           // [16][128][1024]
  bf16* aout  = vT + 2048L * 1024;            // [2048][2048]

  prep<<<dim3(32, 32, 5), 256, 0, stream>>>(x, wq, wk, wv, wo, xb, wqkvT, woT);

  gemm_qkv<<<dim3(16, 16), 512, 0, stream>>>(xb, wqkvT, fc, fs, q0b, k1b, k2b, vT);

  attn_kernel<<<dim3(16, 16, 2), 256, 0, stream>>>(q0b, k1b, k2b, vT, fc, fs, aout);

  gemm_bt128<<<dim3(16, 16), 512, 0, stream>>>(aout, woT, out, 2048, 2048, 2048);
}